// Round 14
// baseline (178.138 us; speedup 1.0000x reference)
//
#include <hip/hip_runtime.h>
#include <hip/hip_bf16.h>

#define N_NODES 20000
#define N_EDGES 150000
#define D 512
#define KK 2048          // GEMM K: 3 rel slots (in A) + 1 self slot (from xb)
#define KREL 1536        // A row stride (3 rel slots only)
#define NROWS 20480
#define NTILES_M 160     // 128-row M tiles

typedef __attribute__((ext_vector_type(8))) short bf16x8_t;
typedef __attribute__((ext_vector_type(4))) float f32x4_t;

// ---- helpers ----
__device__ __forceinline__ unsigned short f2bf(float x) {
    unsigned u = __float_as_uint(x);
    unsigned r = u + 0x7fffu + ((u >> 16) & 1u);   // RNE
    return (unsigned short)(r >> 16);
}
__device__ __forceinline__ unsigned pack2(float a, float b) {
    return (unsigned)f2bf(a) | ((unsigned)f2bf(b) << 16);
}
__device__ __forceinline__ float bflo(unsigned u) { return __uint_as_float(u << 16); }
__device__ __forceinline__ float bfhi(unsigned u) { return __uint_as_float(u & 0xffff0000u); }

#define GL(g, l)                                                                        \
    __builtin_amdgcn_global_load_lds(                                                   \
        (const __attribute__((address_space(1))) unsigned*)(g),                         \
        (__attribute__((address_space(3))) unsigned*)(l), 16, 0, 0)

// ---- fused prep: transpose_B (384 blocks) | conv_x (5000) | count (587) ----
#define TB_BLOCKS 384
#define CX_BLOCKS 5000
#define CNT_BLOCKS 587
__global__ __launch_bounds__(256) void fused_prep(
    const float* __restrict__ W_rel, const float* __restrict__ W_self,
    short* __restrict__ Bt,
    const float* __restrict__ x, short* __restrict__ xb,
    const int* __restrict__ edst, int* __restrict__ hist,
    const int* __restrict__ ntype, int* __restrict__ tcnt) {
    __shared__ float tile[64][65];
    const int b = blockIdx.x;
    if (b < TB_BLOCKS) {
        const int z = b >> 6;                         // 0..5
        const int rem = b & 63;
        const int e0 = (rem & 7) * 64, d0 = (rem >> 3) * 64;
        const float* src = (z < 3) ? (W_rel + (size_t)z * D * D)
                                   : (W_self + (size_t)(z - 3) * D * D);
        const int cbase = (z < 3) ? z * 512 : KREL + (z - 3) * 512;
        const int tx = threadIdx.x & 63, ty = threadIdx.x >> 6;
#pragma unroll
        for (int j = 0; j < 16; ++j) {
            int dl = ty * 16 + j;
            tile[dl][tx] = src[(size_t)(d0 + dl) * D + e0 + tx];
        }
        __syncthreads();
#pragma unroll
        for (int j = 0; j < 16; ++j) {
            int el = ty * 16 + j;
            Bt[(size_t)(e0 + el) * 3072 + cbase + d0 + tx] = (short)f2bf(tile[tx][el]);
        }
    } else if (b < TB_BLOCKS + CX_BLOCKS) {
        int idx = (b - TB_BLOCKS) * 256 + threadIdx.x;   // < 1,280,000
        const float4* s = (const float4*)x + (size_t)idx * 2;
        float4 a = s[0], bb = s[1];
        uint4 pk;
        pk.x = pack2(a.x, a.y);  pk.y = pack2(a.z, a.w);
        pk.z = pack2(bb.x, bb.y); pk.w = pack2(bb.z, bb.w);
        ((uint4*)xb)[idx] = pk;
    } else {
        int i = (b - TB_BLOCKS - CX_BLOCKS) * 256 + threadIdx.x;
        if (i < N_EDGES) atomicAdd(&hist[edst[i]], 1);
        int lane = threadIdx.x & 63;
        int t = (i < N_NODES) ? ntype[i] : 3;
        unsigned long long m0 = __ballot(t == 0), m1 = __ballot(t == 1), m2 = __ballot(t == 2);
        if (lane == 0) {
            if (m0) atomicAdd(&tcnt[0], __popcll(m0));
            if (m1) atomicAdd(&tcnt[1], __popcll(m1));
            if (m2) atomicAdd(&tcnt[2], __popcll(m2));
        }
    }
}

// ---- scan of 20000 edge-bins -> offs/cur; typeoff; rowmap padding marks ----
__global__ __launch_bounds__(1024) void scan_k(const int* __restrict__ hist,
                                               int* __restrict__ offs,
                                               int* __restrict__ cur,
                                               const int* __restrict__ tcnt,
                                               int* __restrict__ typeoff,
                                               int* __restrict__ rowmap) {
    __shared__ int part[1024];
    const int t = threadIdx.x;
    const int base = t * 20;
    int local[20];
    int sum = 0;
#pragma unroll
    for (int i = 0; i < 20; ++i) {
        int b = base + i;
        int v = (b < N_NODES) ? hist[b] : 0;
        local[i] = sum;
        sum += v;
    }
    part[t] = sum;
    __syncthreads();
    for (int off = 1; off < 1024; off <<= 1) {
        int v = part[t];
        int u = (t >= off) ? part[t - off] : 0;
        __syncthreads();
        part[t] = v + u;
        __syncthreads();
    }
    int tbase = (t > 0) ? part[t - 1] : 0;
#pragma unroll
    for (int i = 0; i < 20; ++i) {
        int b = base + i;
        if (b < N_NODES) {
            int o = tbase + local[i];
            offs[b] = o;
            cur[b] = o;
        }
    }
    if (t == 1023) offs[N_NODES] = part[1023];

    int c0 = tcnt[0], c1 = tcnt[1], c2 = tcnt[2];
    int o1 = (c0 + 127) & ~127;
    int o2 = o1 + ((c1 + 127) & ~127);
    int o3 = o2 + ((c2 + 127) & ~127);
    if (t == 0) { typeoff[0] = 0; typeoff[1] = o1; typeoff[2] = o2; typeoff[3] = o3; }
    int p0 = o1 - c0, p1 = o2 - o1 - c1, p2 = o3 - o2 - c2;
    if (t < p0) rowmap[c0 + t] = -1;
    else if (t < p0 + p1) rowmap[o1 + c1 + (t - p0)] = -1;
    else if (t - p0 - p1 < p2) rowmap[o2 + c2 + (t - p0 - p1)] = -1;
}

// ---- node->row assignment (type-grouped) + edge-id scatter (fused) ----
__global__ __launch_bounds__(256) void assign_scatter_k(
    const int* __restrict__ ntype, const int* __restrict__ typeoff,
    int* __restrict__ tcur, int* __restrict__ noderow, int* __restrict__ rowmap,
    const int* __restrict__ esrc, const int* __restrict__ edst,
    const int* __restrict__ etyp, int* __restrict__ cur, int* __restrict__ sorted) {
    int i = blockIdx.x * 256 + threadIdx.x;
    int lane = threadIdx.x & 63;
    bool valid = i < N_NODES;
    int t = valid ? ntype[i] : 3;
    unsigned long long m0 = __ballot(t == 0), m1 = __ballot(t == 1), m2 = __ballot(t == 2);
    unsigned long long below = (lane == 0) ? 0ull : (~0ull >> (64 - lane));
    int b0 = 0, b1 = 0, b2 = 0;
    if (lane == 0) {
        if (m0) b0 = atomicAdd(&tcur[0], __popcll(m0));
        if (m1) b1 = atomicAdd(&tcur[1], __popcll(m1));
        if (m2) b2 = atomicAdd(&tcur[2], __popcll(m2));
    }
    b0 = __shfl(b0, 0); b1 = __shfl(b1, 0); b2 = __shfl(b2, 0);
    if (valid) {
        unsigned long long mk = (t == 0) ? m0 : (t == 1) ? m1 : m2;
        int bs = (t == 0) ? b0 : (t == 1) ? b1 : b2;
        int row = typeoff[t] + bs + __popcll(mk & below);
        noderow[i] = row;
        rowmap[row] = i;
    }
    if (i < N_EDGES) {
        int dst = edst[i];
        int pos = atomicAdd(&cur[dst], 1);
        sorted[pos] = esrc[i] | (etyp[i] << 16);
    }
}

// ---- aggregate: 2 nodes per wave, 8 gathers in flight; linear A writes ----
#define DECL_ACC(P)                                                                   \
    float P##00=0,P##01=0,P##02=0,P##03=0,P##04=0,P##05=0,P##06=0,P##07=0,            \
          P##10=0,P##11=0,P##12=0,P##13=0,P##14=0,P##15=0,P##16=0,P##17=0,            \
          P##20=0,P##21=0,P##22=0,P##23=0,P##24=0,P##25=0,P##26=0,P##27=0;            \
    int P##c0=0, P##c1=0, P##c2=0;

#define ACC_E(P, r, v) {                                                              \
    float f0=bflo(v.x),f1=bfhi(v.x),f2=bflo(v.y),f3=bfhi(v.y);                        \
    float f4=bflo(v.z),f5=bfhi(v.z),f6=bflo(v.w),f7=bfhi(v.w);                        \
    if ((r)==0){P##00+=f0;P##01+=f1;P##02+=f2;P##03+=f3;P##04+=f4;P##05+=f5;P##06+=f6;P##07+=f7;P##c0++;} \
    else if ((r)==1){P##10+=f0;P##11+=f1;P##12+=f2;P##13+=f3;P##14+=f4;P##15+=f5;P##16+=f6;P##17+=f7;P##c1++;} \
    else {P##20+=f0;P##21+=f1;P##22+=f2;P##23+=f3;P##24+=f4;P##25+=f5;P##26+=f6;P##27+=f7;P##c2++;} }

#define STORE_ACC(P, n) {                                                             \
    const int rowid = noderow[n];                                                     \
    short* row = A + (size_t)rowid * KREL;                                            \
    uint4 q;                                                                          \
    q.x=pack2(P##00,P##01); q.y=pack2(P##02,P##03); q.z=pack2(P##04,P##05); q.w=pack2(P##06,P##07); \
    *(uint4*)(row + 0 * D + lane * 8) = q;                                            \
    q.x=pack2(P##10,P##11); q.y=pack2(P##12,P##13); q.z=pack2(P##14,P##15); q.w=pack2(P##16,P##17); \
    *(uint4*)(row + 1 * D + lane * 8) = q;                                            \
    q.x=pack2(P##20,P##21); q.y=pack2(P##22,P##23); q.z=pack2(P##24,P##25); q.w=pack2(P##26,P##27); \
    *(uint4*)(row + 2 * D + lane * 8) = q;                                            \
    if (lane == 0) { cnt[n]=P##c0; cnt[N_NODES+n]=P##c1; cnt[2*N_NODES+n]=P##c2; } }

__global__ __launch_bounds__(256) void aggregate(const short* __restrict__ xb,
                                                 const int* __restrict__ offs,
                                                 const int* __restrict__ sorted,
                                                 const int* __restrict__ noderow,
                                                 short* __restrict__ A,
                                                 int* __restrict__ cnt) {
    const int wid = threadIdx.x >> 6, lane = threadIdx.x & 63;
    const int n0 = (blockIdx.x * 4 + wid) * 2;
    if (n0 >= N_NODES) return;
    const int n1 = n0 + 1;
    const int s0 = offs[n0], e0 = offs[n0 + 1];
    const int s1 = offs[n1], e1 = offs[n1 + 1];
    const int m0 = e0 - s0, m1 = e1 - s1;

    DECL_ACC(a); DECL_ACC(b);

    int pl0 = (lane < m0) ? sorted[s0 + lane] : 0;
    int pl1 = (lane < m1) ? sorted[s1 + lane] : 0;
    const int mm0 = m0 < 64 ? m0 : 64;
    const int mm1 = m1 < 64 ? m1 : 64;
    const int mmax = mm0 > mm1 ? mm0 : mm1;

    for (int i = 0; i < mmax; i += 4) {
        int pA0 = __shfl(pl0, i), pA1 = __shfl(pl0, i + 1);
        int pA2 = __shfl(pl0, i + 2), pA3 = __shfl(pl0, i + 3);
        int pB0 = __shfl(pl1, i), pB1 = __shfl(pl1, i + 1);
        int pB2 = __shfl(pl1, i + 2), pB3 = __shfl(pl1, i + 3);
        int iA0 = (i     < mm0) ? (pA0 & 0xffff) : 0;
        int iA1 = (i + 1 < mm0) ? (pA1 & 0xffff) : 0;
        int iA2 = (i + 2 < mm0) ? (pA2 & 0xffff) : 0;
        int iA3 = (i + 3 < mm0) ? (pA3 & 0xffff) : 0;
        int iB0 = (i     < mm1) ? (pB0 & 0xffff) : 0;
        int iB1 = (i + 1 < mm1) ? (pB1 & 0xffff) : 0;
        int iB2 = (i + 2 < mm1) ? (pB2 & 0xffff) : 0;
        int iB3 = (i + 3 < mm1) ? (pB3 & 0xffff) : 0;
        uint4 vA0 = ((const uint4*)(xb + (size_t)iA0 * D))[lane];
        uint4 vB0 = ((const uint4*)(xb + (size_t)iB0 * D))[lane];
        uint4 vA1 = ((const uint4*)(xb + (size_t)iA1 * D))[lane];
        uint4 vB1 = ((const uint4*)(xb + (size_t)iB1 * D))[lane];
        uint4 vA2 = ((const uint4*)(xb + (size_t)iA2 * D))[lane];
        uint4 vB2 = ((const uint4*)(xb + (size_t)iB2 * D))[lane];
        uint4 vA3 = ((const uint4*)(xb + (size_t)iA3 * D))[lane];
        uint4 vB3 = ((const uint4*)(xb + (size_t)iB3 * D))[lane];
        if (i     < mm0) ACC_E(a, pA0 >> 16, vA0);
        if (i     < mm1) ACC_E(b, pB0 >> 16, vB0);
        if (i + 1 < mm0) ACC_E(a, pA1 >> 16, vA1);
        if (i + 1 < mm1) ACC_E(b, pB1 >> 16, vB1);
        if (i + 2 < mm0) ACC_E(a, pA2 >> 16, vA2);
        if (i + 2 < mm1) ACC_E(b, pB2 >> 16, vB2);
        if (i + 3 < mm0) ACC_E(a, pA3 >> 16, vA3);
        if (i + 3 < mm1) ACC_E(b, pB3 >> 16, vB3);
    }
    for (int j = 64; j < m0; ++j) {      // overflow (essentially never taken)
        int p = sorted[s0 + j];
        uint4 v = ((const uint4*)(xb + (size_t)(p & 0xffff) * D))[lane];
        ACC_E(a, p >> 16, v);
    }
    for (int j = 64; j < m1; ++j) {
        int p = sorted[s1 + j];
        uint4 v = ((const uint4*)(xb + (size_t)(p & 0xffff) * D))[lane];
        ACC_E(b, p >> 16, v);
    }

    STORE_ACC(a, n0);
    STORE_ACC(b, n1);
}

// ---- GEMM: 128x128 tile, BK=128, single 64KB buffer, 8 K-steps (16 barriers) ----
__global__ __launch_bounds__(256, 2) void gemm_bias_relu(
    const short* __restrict__ A, const short* __restrict__ Bt,
    const short* __restrict__ xb, float* __restrict__ out,
    const int* __restrict__ cnt, const float* __restrict__ b_rel,
    const float* __restrict__ b_self, const int* __restrict__ typeoff,
    const int* __restrict__ rowmap) {
    __shared__ short lds[32768];         // A: 128x128 (32KB) then B: 128x128 (32KB)
    const int tid = threadIdx.x;
    const int lane = tid & 63;
    const int wid = tid >> 6;
    const int wm = wid >> 1, wn = wid & 1;
    const int lr = lane & 15, lk = lane >> 4;

    // bijective XCD-chunk swizzle: 640 blocks, 8 XCDs, 80/XCD; tn-siblings adjacent
    const int lin = blockIdx.x;
    const int mapped = (lin & 7) * 80 + (lin >> 3);
    const int tm = mapped >> 2;
    const int tn = mapped & 3;

    const int o1 = typeoff[1], o2 = typeoff[2], Mtot = typeoff[3];
    const int arow0 = tm * 128;
    if (arow0 >= Mtot) return;
    const int ttile = (arow0 >= o2) ? 2 : (arow0 >= o1) ? 1 : 0;
    const int tsel = ttile * 512;
    const int brow0 = tn * 128;

    // staging: A 8 chunks + B 8 chunks/thread; LDS[row][c] = data[row][c^(row&15)]
    const short* aP[8]; const short* xP[8]; const short* bP[8];
#pragma unroll
    for (int j = 0; j < 8; ++j) {
        int p = tid + 256 * j;                  // 0..2047
        int row = p >> 4;                       // 0..127
        int g = (p & 15) ^ (row & 15);
        aP[j] = A + (size_t)(arow0 + row) * KREL + g * 8;
        int nd = rowmap[arow0 + row];
        if (nd < 0) nd = 0;
        xP[j] = xb + (size_t)nd * D + g * 8;
        bP[j] = Bt + (size_t)(brow0 + row) * 3072 + g * 8;
    }
    char* const ldsc = (char*)lds;

#define STAGE(kt) {                                                                   \
    const int k0s = (kt) * 128;                                                       \
    if (k0s < KREL) {                                                                 \
        _Pragma("unroll")                                                             \
        for (int j = 0; j < 8; ++j)                                                   \
            GL(aP[j] + k0s, ldsc + (tid + 256 * j) * 16);                             \
    } else {                                                                          \
        _Pragma("unroll")                                                             \
        for (int j = 0; j < 8; ++j)                                                   \
            GL(xP[j] + (k0s - KREL), ldsc + (tid + 256 * j) * 16);                    \
    }                                                                                 \
    const int bk = k0s + (k0s >= KREL ? tsel : 0);                                    \
    _Pragma("unroll")                                                                 \
    for (int j = 0; j < 8; ++j)                                                       \
        GL(bP[j] + bk, ldsc + 32768 + (tid + 256 * j) * 16);                          \
}

#define COMPUTE() {                                                                   \
    _Pragma("unroll")                                                                 \
    for (int kk = 0; kk < 4; ++kk) {                                                  \
        bf16x8_t af[4], bfr[4];                                                       \
        _Pragma("unroll")                                                             \
        for (int m = 0; m < 4; ++m) {                                                 \
            int row_l = wm * 64 + m * 16 + lr;                                        \
            int pos = (row_l << 4) + ((kk * 4 + lk) ^ (row_l & 15));                  \
            af[m] = *(const bf16x8_t*)&lds[pos << 3];                                 \
        }                                                                             \
        _Pragma("unroll")                                                             \
        for (int n = 0; n < 4; ++n) {                                                 \
            int row_l = wn * 64 + n * 16 + lr;                                        \
            int pos = (row_l << 4) + ((kk * 4 + lk) ^ (row_l & 15));                  \
            bfr[n] = *(const bf16x8_t*)&lds[16384 + (pos << 3)];                      \
        }                                                                             \
        __builtin_amdgcn_s_setprio(1);                                                \
        _Pragma("unroll")                                                             \
        for (int m = 0; m < 4; ++m)                                                   \
            _Pragma("unroll")                                                         \
            for (int n = 0; n < 4; ++n)                                               \
                acc[m][n] = __builtin_amdgcn_mfma_f32_16x16x32_bf16(                  \
                    af[m], bfr[n], acc[m][n], 0, 0, 0);                               \
        __builtin_amdgcn_s_setprio(0);                                                \
    }                                                                                 \
}

    f32x4_t acc[4][4] = {};

    STAGE(0);
    __syncthreads();             // vmcnt-drain + barrier: tile 0 ready
#pragma unroll 1
    for (int kt = 0; kt < 16; ++kt) {
        COMPUTE();
        __syncthreads();         // all waves done reading before overwrite
        if (kt + 1 < 16) {
            STAGE(kt + 1);
            __syncthreads();     // drain + barrier: next tile ready
        }
    }

#pragma unroll
    for (int m = 0; m < 4; ++m) {
#pragma unroll
        for (int q = 0; q < 4; ++q) {
            int rowg = arow0 + wm * 64 + m * 16 + lk * 4 + q;
            int node = rowmap[rowg];
            if (node < 0) continue;
            float c0 = (float)cnt[node];
            float c1 = (float)cnt[N_NODES + node];
            float c2 = (float)cnt[2 * N_NODES + node];
#pragma unroll
            for (int n = 0; n < 4; ++n) {
                int colg = tn * 128 + wn * 64 + n * 16 + lr;
                float v = acc[m][n][q];
                v += c0 * b_rel[colg] + c1 * b_rel[D + colg] + c2 * b_rel[2 * D + colg];
                v += b_self[tsel + colg];
                v = v > 0.f ? v : 0.f;
                out[(size_t)node * D + colg] = v;
            }
        }
    }
}

extern "C" void kernel_launch(void* const* d_in, const int* in_sizes, int n_in,
                              void* d_out, int out_size, void* d_ws, size_t ws_size,
                              hipStream_t stream) {
    const float* x      = (const float*)d_in[0];
    const float* W_rel  = (const float*)d_in[1];
    const float* b_rel  = (const float*)d_in[2];
    const float* W_self = (const float*)d_in[3];
    const float* b_self = (const float*)d_in[4];
    const int* esrc     = (const int*)d_in[5];
    const int* edst     = (const int*)d_in[6];
    const int* etyp     = (const int*)d_in[7];
    const int* ntyp     = (const int*)d_in[8];
    float* out = (float*)d_out;

    char* ws = (char*)d_ws;
    size_t o = 0;
    short* A       = (short*)(ws + o); o += (size_t)NROWS * KREL * 2;    // 62,914,560
    short* Bt      = (short*)(ws + o); o += (size_t)D * 3072 * 2;        // 3,145,728
    short* xb      = (short*)(ws + o); o += (size_t)N_NODES * D * 2;     // 20,480,000
    int*   cnt     = (int*)(ws + o);   o += (size_t)3 * N_NODES * 4;     // 240,000
    int*   offs    = (int*)(ws + o);   o += 80032;
    int*   cur     = (int*)(ws + o);   o += 80000;
    int*   noderow = (int*)(ws + o);   o += 80000;
    int*   rowmap  = (int*)(ws + o);   o += (size_t)NROWS * 4;           // 81,920
    int*   sorted  = (int*)(ws + o);   o += 600000;
    // zero-region (memset): hist + tcnt + tcur + typeoff, contiguous 80048 B
    int*   hist    = (int*)(ws + o);   o += 80000;
    int*   tcnt    = (int*)(ws + o);   o += 16;
    int*   tcur    = (int*)(ws + o);   o += 16;
    int*   typeoff = (int*)(ws + o);   o += 16;

    hipMemsetAsync(hist, 0, 80048, stream);
    fused_prep<<<TB_BLOCKS + CX_BLOCKS + CNT_BLOCKS, 256, 0, stream>>>(
        W_rel, W_self, Bt, x, xb, edst, hist, ntyp, tcnt);
    scan_k<<<1, 1024, 0, stream>>>(hist, offs, cur, tcnt, typeoff, rowmap);
    assign_scatter_k<<<(N_EDGES + 255) / 256, 256, 0, stream>>>(
        ntyp, typeoff, tcur, noderow, rowmap, esrc, edst, etyp, cur, sorted);
    aggregate<<<(N_NODES / 2 + 3) / 4, 256, 0, stream>>>(xb, offs, sorted, noderow, A, cnt);
    gemm_bias_relu<<<NTILES_M * 4, 256, 0, stream>>>(A, Bt, xb, out, cnt, b_rel, b_self,
                                                     typeoff, rowmap);
}

// Round 16
// 172.268 us; speedup vs baseline: 1.0341x; 1.0341x over previous
//
#include <hip/hip_runtime.h>
#include <hip/hip_bf16.h>

#define N_NODES 20000
#define N_EDGES 150000
#define D 512
#define KK 2048          // GEMM K: 3 rel slots (in A) + 1 self slot (from xb)
#define KREL 1536        // A row stride (3 rel slots only)
#define NROWS 20480
#define NTILES_M 320     // 64-row M tiles

typedef __attribute__((ext_vector_type(8))) short bf16x8_t;
typedef __attribute__((ext_vector_type(4))) float f32x4_t;
typedef __attribute__((ext_vector_type(4))) unsigned u32x4_t;

// ---- helpers ----
__device__ __forceinline__ unsigned short f2bf(float x) {
    unsigned u = __float_as_uint(x);
    unsigned r = u + 0x7fffu + ((u >> 16) & 1u);   // RNE
    return (unsigned short)(r >> 16);
}
__device__ __forceinline__ unsigned pack2(float a, float b) {
    return (unsigned)f2bf(a) | ((unsigned)f2bf(b) << 16);
}
__device__ __forceinline__ float bflo(unsigned u) { return __uint_as_float(u << 16); }
__device__ __forceinline__ float bfhi(unsigned u) { return __uint_as_float(u & 0xffff0000u); }

#define GL(g, l)                                                                        \
    __builtin_amdgcn_global_load_lds(                                                   \
        (const __attribute__((address_space(1))) unsigned*)(g),                         \
        (__attribute__((address_space(3))) unsigned*)(l), 16, 0, 0)

// ---- fused prep: transpose_B (384 blocks) | conv_x (5000) | count (587) ----
#define TB_BLOCKS 384
#define CX_BLOCKS 5000
#define CNT_BLOCKS 587
__global__ __launch_bounds__(256) void fused_prep(
    const float* __restrict__ W_rel, const float* __restrict__ W_self,
    short* __restrict__ Bt,
    const float* __restrict__ x, short* __restrict__ xb,
    const int* __restrict__ edst, int* __restrict__ hist,
    const int* __restrict__ ntype, int* __restrict__ tcnt) {
    __shared__ float tile[64][65];
    const int b = blockIdx.x;
    if (b < TB_BLOCKS) {
        const int z = b >> 6;                         // 0..5
        const int rem = b & 63;
        const int e0 = (rem & 7) * 64, d0 = (rem >> 3) * 64;
        const float* src = (z < 3) ? (W_rel + (size_t)z * D * D)
                                   : (W_self + (size_t)(z - 3) * D * D);
        const int cbase = (z < 3) ? z * 512 : KREL + (z - 3) * 512;
        const int tx = threadIdx.x & 63, ty = threadIdx.x >> 6;
#pragma unroll
        for (int j = 0; j < 16; ++j) {
            int dl = ty * 16 + j;
            tile[dl][tx] = src[(size_t)(d0 + dl) * D + e0 + tx];
        }
        __syncthreads();
#pragma unroll
        for (int j = 0; j < 16; ++j) {
            int el = ty * 16 + j;
            Bt[(size_t)(e0 + el) * 3072 + cbase + d0 + tx] = (short)f2bf(tile[tx][el]);
        }
    } else if (b < TB_BLOCKS + CX_BLOCKS) {
        int idx = (b - TB_BLOCKS) * 256 + threadIdx.x;   // < 1,280,000
        const float4* s = (const float4*)x + (size_t)idx * 2;
        float4 a = s[0], bb = s[1];
        uint4 pk;
        pk.x = pack2(a.x, a.y);  pk.y = pack2(a.z, a.w);
        pk.z = pack2(bb.x, bb.y); pk.w = pack2(bb.z, bb.w);
        ((uint4*)xb)[idx] = pk;
    } else {
        int i = (b - TB_BLOCKS - CX_BLOCKS) * 256 + threadIdx.x;
        if (i < N_EDGES) atomicAdd(&hist[edst[i]], 1);
        int lane = threadIdx.x & 63;
        int t = (i < N_NODES) ? ntype[i] : 3;
        unsigned long long m0 = __ballot(t == 0), m1 = __ballot(t == 1), m2 = __ballot(t == 2);
        if (lane == 0) {
            if (m0) atomicAdd(&tcnt[0], __popcll(m0));
            if (m1) atomicAdd(&tcnt[1], __popcll(m1));
            if (m2) atomicAdd(&tcnt[2], __popcll(m2));
        }
    }
}

// ---- scan of 20000 edge-bins -> offs/cur; typeoff; rowmap padding marks ----
__global__ __launch_bounds__(1024) void scan_k(const int* __restrict__ hist,
                                               int* __restrict__ offs,
                                               int* __restrict__ cur,
                                               const int* __restrict__ tcnt,
                                               int* __restrict__ typeoff,
                                               int* __restrict__ rowmap) {
    __shared__ int part[1024];
    const int t = threadIdx.x;
    const int base = t * 20;
    int local[20];
    int sum = 0;
#pragma unroll
    for (int i = 0; i < 20; ++i) {
        int b = base + i;
        int v = (b < N_NODES) ? hist[b] : 0;
        local[i] = sum;
        sum += v;
    }
    part[t] = sum;
    __syncthreads();
    for (int off = 1; off < 1024; off <<= 1) {
        int v = part[t];
        int u = (t >= off) ? part[t - off] : 0;
        __syncthreads();
        part[t] = v + u;
        __syncthreads();
    }
    int tbase = (t > 0) ? part[t - 1] : 0;
#pragma unroll
    for (int i = 0; i < 20; ++i) {
        int b = base + i;
        if (b < N_NODES) {
            int o = tbase + local[i];
            offs[b] = o;
            cur[b] = o;
        }
    }
    if (t == 1023) offs[N_NODES] = part[1023];

    int c0 = tcnt[0], c1 = tcnt[1], c2 = tcnt[2];
    int o1 = (c0 + 127) & ~127;
    int o2 = o1 + ((c1 + 127) & ~127);
    int o3 = o2 + ((c2 + 127) & ~127);
    if (t == 0) { typeoff[0] = 0; typeoff[1] = o1; typeoff[2] = o2; typeoff[3] = o3; }
    int p0 = o1 - c0, p1 = o2 - o1 - c1, p2 = o3 - o2 - c2;
    if (t < p0) rowmap[c0 + t] = -1;
    else if (t < p0 + p1) rowmap[o1 + c1 + (t - p0)] = -1;
    else if (t - p0 - p1 < p2) rowmap[o2 + c2 + (t - p0 - p1)] = -1;
}

// ---- node->row assignment (type-grouped) + edge-id scatter (fused) ----
__global__ __launch_bounds__(256) void assign_scatter_k(
    const int* __restrict__ ntype, const int* __restrict__ typeoff,
    int* __restrict__ tcur, int* __restrict__ noderow, int* __restrict__ rowmap,
    const int* __restrict__ esrc, const int* __restrict__ edst,
    const int* __restrict__ etyp, int* __restrict__ cur, int* __restrict__ sorted) {
    int i = blockIdx.x * 256 + threadIdx.x;
    int lane = threadIdx.x & 63;
    bool valid = i < N_NODES;
    int t = valid ? ntype[i] : 3;
    unsigned long long m0 = __ballot(t == 0), m1 = __ballot(t == 1), m2 = __ballot(t == 2);
    unsigned long long below = (lane == 0) ? 0ull : (~0ull >> (64 - lane));
    int b0 = 0, b1 = 0, b2 = 0;
    if (lane == 0) {
        if (m0) b0 = atomicAdd(&tcur[0], __popcll(m0));
        if (m1) b1 = atomicAdd(&tcur[1], __popcll(m1));
        if (m2) b2 = atomicAdd(&tcur[2], __popcll(m2));
    }
    b0 = __shfl(b0, 0); b1 = __shfl(b1, 0); b2 = __shfl(b2, 0);
    if (valid) {
        unsigned long long mk = (t == 0) ? m0 : (t == 1) ? m1 : m2;
        int bs = (t == 0) ? b0 : (t == 1) ? b1 : b2;
        int row = typeoff[t] + bs + __popcll(mk & below);
        noderow[i] = row;
        rowmap[row] = i;
    }
    if (i < N_EDGES) {
        int dst = edst[i];
        int pos = atomicAdd(&cur[dst], 1);
        sorted[pos] = esrc[i] | (etyp[i] << 16);
    }
}

// ---- aggregate: 2 nodes per wave, 8 gathers in flight; NT linear A writes ----
#define DECL_ACC(P)                                                                   \
    float P##00=0,P##01=0,P##02=0,P##03=0,P##04=0,P##05=0,P##06=0,P##07=0,            \
          P##10=0,P##11=0,P##12=0,P##13=0,P##14=0,P##15=0,P##16=0,P##17=0,            \
          P##20=0,P##21=0,P##22=0,P##23=0,P##24=0,P##25=0,P##26=0,P##27=0;            \
    int P##c0=0, P##c1=0, P##c2=0;

#define ACC_E(P, r, v) {                                                              \
    float f0=bflo(v.x),f1=bfhi(v.x),f2=bflo(v.y),f3=bfhi(v.y);                        \
    float f4=bflo(v.z),f5=bfhi(v.z),f6=bflo(v.w),f7=bfhi(v.w);                        \
    if ((r)==0){P##00+=f0;P##01+=f1;P##02+=f2;P##03+=f3;P##04+=f4;P##05+=f5;P##06+=f6;P##07+=f7;P##c0++;} \
    else if ((r)==1){P##10+=f0;P##11+=f1;P##12+=f2;P##13+=f3;P##14+=f4;P##15+=f5;P##16+=f6;P##17+=f7;P##c1++;} \
    else {P##20+=f0;P##21+=f1;P##22+=f2;P##23+=f3;P##24+=f4;P##25+=f5;P##26+=f6;P##27+=f7;P##c2++;} }

#define STORE_ACC(P, n) {                                                             \
    const int rowid = noderow[n];                                                     \
    short* row = A + (size_t)rowid * KREL;                                            \
    u32x4_t q;                                                                        \
    q.x=pack2(P##00,P##01); q.y=pack2(P##02,P##03); q.z=pack2(P##04,P##05); q.w=pack2(P##06,P##07); \
    __builtin_nontemporal_store(q, (u32x4_t*)(row + 0 * D + lane * 8));               \
    q.x=pack2(P##10,P##11); q.y=pack2(P##12,P##13); q.z=pack2(P##14,P##15); q.w=pack2(P##16,P##17); \
    __builtin_nontemporal_store(q, (u32x4_t*)(row + 1 * D + lane * 8));               \
    q.x=pack2(P##20,P##21); q.y=pack2(P##22,P##23); q.z=pack2(P##24,P##25); q.w=pack2(P##26,P##27); \
    __builtin_nontemporal_store(q, (u32x4_t*)(row + 2 * D + lane * 8));               \
    if (lane == 0) { cnt[n]=P##c0; cnt[N_NODES+n]=P##c1; cnt[2*N_NODES+n]=P##c2; } }

__global__ __launch_bounds__(256) void aggregate(const short* __restrict__ xb,
                                                 const int* __restrict__ offs,
                                                 const int* __restrict__ sorted,
                                                 const int* __restrict__ noderow,
                                                 short* __restrict__ A,
                                                 int* __restrict__ cnt) {
    const int wid = threadIdx.x >> 6, lane = threadIdx.x & 63;
    const int n0 = (blockIdx.x * 4 + wid) * 2;
    if (n0 >= N_NODES) return;
    const int n1 = n0 + 1;
    const int s0 = offs[n0], e0 = offs[n0 + 1];
    const int s1 = offs[n1], e1 = offs[n1 + 1];
    const int m0 = e0 - s0, m1 = e1 - s1;

    DECL_ACC(a); DECL_ACC(b);

    int pl0 = (lane < m0) ? sorted[s0 + lane] : 0;
    int pl1 = (lane < m1) ? sorted[s1 + lane] : 0;
    const int mm0 = m0 < 64 ? m0 : 64;
    const int mm1 = m1 < 64 ? m1 : 64;
    const int mmax = mm0 > mm1 ? mm0 : mm1;

    for (int i = 0; i < mmax; i += 4) {
        int pA0 = __shfl(pl0, i), pA1 = __shfl(pl0, i + 1);
        int pA2 = __shfl(pl0, i + 2), pA3 = __shfl(pl0, i + 3);
        int pB0 = __shfl(pl1, i), pB1 = __shfl(pl1, i + 1);
        int pB2 = __shfl(pl1, i + 2), pB3 = __shfl(pl1, i + 3);
        int iA0 = (i     < mm0) ? (pA0 & 0xffff) : 0;
        int iA1 = (i + 1 < mm0) ? (pA1 & 0xffff) : 0;
        int iA2 = (i + 2 < mm0) ? (pA2 & 0xffff) : 0;
        int iA3 = (i + 3 < mm0) ? (pA3 & 0xffff) : 0;
        int iB0 = (i     < mm1) ? (pB0 & 0xffff) : 0;
        int iB1 = (i + 1 < mm1) ? (pB1 & 0xffff) : 0;
        int iB2 = (i + 2 < mm1) ? (pB2 & 0xffff) : 0;
        int iB3 = (i + 3 < mm1) ? (pB3 & 0xffff) : 0;
        uint4 vA0 = ((const uint4*)(xb + (size_t)iA0 * D))[lane];
        uint4 vB0 = ((const uint4*)(xb + (size_t)iB0 * D))[lane];
        uint4 vA1 = ((const uint4*)(xb + (size_t)iA1 * D))[lane];
        uint4 vB1 = ((const uint4*)(xb + (size_t)iB1 * D))[lane];
        uint4 vA2 = ((const uint4*)(xb + (size_t)iA2 * D))[lane];
        uint4 vB2 = ((const uint4*)(xb + (size_t)iB2 * D))[lane];
        uint4 vA3 = ((const uint4*)(xb + (size_t)iA3 * D))[lane];
        uint4 vB3 = ((const uint4*)(xb + (size_t)iB3 * D))[lane];
        if (i     < mm0) ACC_E(a, pA0 >> 16, vA0);
        if (i     < mm1) ACC_E(b, pB0 >> 16, vB0);
        if (i + 1 < mm0) ACC_E(a, pA1 >> 16, vA1);
        if (i + 1 < mm1) ACC_E(b, pB1 >> 16, vB1);
        if (i + 2 < mm0) ACC_E(a, pA2 >> 16, vA2);
        if (i + 2 < mm1) ACC_E(b, pB2 >> 16, vB2);
        if (i + 3 < mm0) ACC_E(a, pA3 >> 16, vA3);
        if (i + 3 < mm1) ACC_E(b, pB3 >> 16, vB3);
    }
    for (int j = 64; j < m0; ++j) {      // overflow (essentially never taken)
        int p = sorted[s0 + j];
        uint4 v = ((const uint4*)(xb + (size_t)(p & 0xffff) * D))[lane];
        ACC_E(a, p >> 16, v);
    }
    for (int j = 64; j < m1; ++j) {
        int p = sorted[s1 + j];
        uint4 v = ((const uint4*)(xb + (size_t)(p & 0xffff) * D))[lane];
        ACC_E(b, p >> 16, v);
    }

    STORE_ACC(a, n0);
    STORE_ACC(b, n1);
}

// ---- GEMM: 64x128 tile, BK=128, single 48KB buffer, 2-barrier loop (R13) ----
__global__ __launch_bounds__(256, 3) void gemm_bias_relu(
    const short* __restrict__ A, const short* __restrict__ Bt,
    const short* __restrict__ xb, float* __restrict__ out,
    const int* __restrict__ cnt, const float* __restrict__ b_rel,
    const float* __restrict__ b_self, const int* __restrict__ typeoff,
    const int* __restrict__ rowmap) {
    __shared__ short lds[24576];         // A: 64x128 (16KB) then B: 128x128 (32KB)
    const int tid = threadIdx.x;
    const int lane = tid & 63;
    const int wid = tid >> 6;
    const int wm = wid >> 1, wn = wid & 1;
    const int lr = lane & 15, lk = lane >> 4;

    // bijective XCD-chunk swizzle: 1280 blocks, 8 XCDs, 160/XCD; tn-siblings adjacent
    const int lin = blockIdx.x;
    const int mapped = (lin & 7) * 160 + (lin >> 3);
    const int tm = mapped >> 2;
    const int tn = mapped & 3;

    const int o1 = typeoff[1], o2 = typeoff[2], Mtot = typeoff[3];
    const int arow0 = tm * 64;
    if (arow0 >= Mtot) return;
    const int ttile = (arow0 >= o2) ? 2 : (arow0 >= o1) ? 1 : 0;
    const int tsel = ttile * 512;
    const int brow0 = tn * 128;

    // staging: A 4 chunks + B 8 chunks per thread; LDS[row][c] = data[row][c^(row&15)]
    const short* aP[4]; const short* xP[4]; const short* bP[8];
#pragma unroll
    for (int j = 0; j < 4; ++j) {
        int p = tid + 256 * j;                  // 0..1023
        int row = p >> 4;                       // 0..63
        int g = (p & 15) ^ (row & 15);
        aP[j] = A + (size_t)(arow0 + row) * KREL + g * 8;
        int nd = rowmap[arow0 + row];
        if (nd < 0) nd = 0;
        xP[j] = xb + (size_t)nd * D + g * 8;
    }
#pragma unroll
    for (int j = 0; j < 8; ++j) {
        int p = tid + 256 * j;                  // 0..2047
        int row = p >> 4;                       // 0..127
        int g = (p & 15) ^ (row & 15);
        bP[j] = Bt + (size_t)(brow0 + row) * 3072 + g * 8;
    }
    char* const ldsc = (char*)lds;

#define STAGE(kt) {                                                                   \
    const int k0s = (kt) * 128;                                                       \
    if (k0s < KREL) {                                                                 \
        _Pragma("unroll")                                                             \
        for (int j = 0; j < 4; ++j)                                                   \
            GL(aP[j] + k0s, ldsc + (tid + 256 * j) * 16);                             \
    } else {                                                                          \
        _Pragma("unroll")                                                             \
        for (int j = 0; j < 4; ++j)                                                   \
            GL(xP[j] + (k0s - KREL), ldsc + (tid + 256 * j) * 16);                    \
    }                                                                                 \
    const int bk = k0s + (k0s >= KREL ? tsel : 0);                                    \
    _Pragma("unroll")                                                                 \
    for (int j = 0; j < 8; ++j)                                                       \
        GL(bP[j] + bk, ldsc + 16384 + (tid + 256 * j) * 16);                          \
}

#define COMPUTE() {                                                                   \
    _Pragma("unroll")                                                                 \
    for (int kk = 0; kk < 4; ++kk) {                                                  \
        bf16x8_t af[2], bfr[4];                                                       \
        _Pragma("unroll")                                                             \
        for (int m = 0; m < 2; ++m) {                                                 \
            int row_l = wm * 32 + m * 16 + lr;                                        \
            int pos = (row_l << 4) + ((kk * 4 + lk) ^ (row_l & 15));                  \
            af[m] = *(const bf16x8_t*)&lds[pos << 3];                                 \
        }                                                                             \
        _Pragma("unroll")                                                             \
        for (int n = 0; n < 4; ++n) {                                                 \
            int row_l = wn * 64 + n * 16 + lr;                                        \
            int pos = (row_l << 4) + ((kk * 4 + lk) ^ (row_l & 15));                  \
            bfr[n] = *(const bf16x8_t*)&lds[8192 + (pos << 3)];                       \
        }                                                                             \
        __builtin_amdgcn_s_setprio(1);                                                \
        _Pragma("unroll")                                                             \
        for (int m = 0; m < 2; ++m)                                                   \
            _Pragma("unroll")                                                         \
            for (int n = 0; n < 4; ++n)                                               \
                acc[m][n] = __builtin_amdgcn_mfma_f32_16x16x32_bf16(                  \
                    af[m], bfr[n], acc[m][n], 0, 0, 0);                               \
        __builtin_amdgcn_s_setprio(0);                                                \
    }                                                                                 \
}

    f32x4_t acc[2][4] = {};

    STAGE(0);
    __syncthreads();             // vmcnt-drain + barrier: tile 0 ready
#pragma unroll 1
    for (int kt = 0; kt < 16; ++kt) {
        COMPUTE();
        __syncthreads();         // all waves done reading before overwrite
        if (kt + 1 < 16) {
            STAGE(kt + 1);
            __syncthreads();     // drain + barrier: next tile ready
        }
    }

#pragma unroll
    for (int m = 0; m < 2; ++m) {
#pragma unroll
        for (int q = 0; q < 4; ++q) {
            int rowg = arow0 + wm * 32 + m * 16 + lk * 4 + q;
            int node = rowmap[rowg];
            if (node < 0) continue;
            float c0 = (float)cnt[node];
            float c1 = (float)cnt[N_NODES + node];
            float c2 = (float)cnt[2 * N_NODES + node];
#pragma unroll
            for (int n = 0; n < 4; ++n) {
                int colg = tn * 128 + wn * 64 + n * 16 + lr;
                float v = acc[m][n][q];
                v += c0 * b_rel[colg] + c1 * b_rel[D + colg] + c2 * b_rel[2 * D + colg];
                v += b_self[tsel + colg];
                v = v > 0.f ? v : 0.f;
                __builtin_nontemporal_store(v, &out[(size_t)node * D + colg]);
            }
        }
    }
}

extern "C" void kernel_launch(void* const* d_in, const int* in_sizes, int n_in,
                              void* d_out, int out_size, void* d_ws, size_t ws_size,
                              hipStream_t stream) {
    const float* x      = (const float*)d_in[0];
    const float* W_rel  = (const float*)d_in[1];
    const float* b_rel  = (const float*)d_in[2];
    const float* W_self = (const float*)d_in[3];
    const float* b_self = (const float*)d_in[4];
    const int* esrc     = (const int*)d_in[5];
    const int* edst     = (const int*)d_in[6];
    const int* etyp     = (const int*)d_in[7];
    const int* ntyp     = (const int*)d_in[8];
    float* out = (float*)d_out;

    char* ws = (char*)d_ws;
    size_t o = 0;
    short* A       = (short*)(ws + o); o += (size_t)NROWS * KREL * 2;    // 62,914,560
    short* Bt      = (short*)(ws + o); o += (size_t)D * 3072 * 2;        // 3,145,728
    short* xb      = (short*)(ws + o); o += (size_t)N_NODES * D * 2;     // 20,480,000
    int*   cnt     = (int*)(ws + o);   o += (size_t)3 * N_NODES * 4;     // 240,000
    int*   offs    = (int*)(ws + o);   o += 80032;
    int*   cur     = (int*)(ws + o);   o += 80000;
    int*   noderow = (int*)(ws + o);   o += 80000;
    int*   rowmap  = (int*)(ws + o);   o += (size_t)NROWS * 4;           // 81,920
    int*   sorted  = (int*)(ws + o);   o += 600000;
    // zero-region (memset): hist + tcnt + tcur + typeoff, contiguous 80048 B
    int*   hist    = (int*)(ws + o);   o += 80000;
    int*   tcnt    = (int*)(ws + o);   o += 16;
    int*   tcur    = (int*)(ws + o);   o += 16;
    int*   typeoff = (int*)(ws + o);   o += 16;

    hipMemsetAsync(hist, 0, 80048, stream);
    fused_prep<<<TB_BLOCKS + CX_BLOCKS + CNT_BLOCKS, 256, 0, stream>>>(
        W_rel, W_self, Bt, x, xb, edst, hist, ntyp, tcnt);
    scan_k<<<1, 1024, 0, stream>>>(hist, offs, cur, tcnt, typeoff, rowmap);
    assign_scatter_k<<<(N_EDGES + 255) / 256, 256, 0, stream>>>(
        ntyp, typeoff, tcur, noderow, rowmap, esrc, edst, etyp, cur, sorted);
    aggregate<<<(N_NODES / 2 + 3) / 4, 256, 0, stream>>>(xb, offs, sorted, noderow, A, cnt);
    gemm_bias_relu<<<NTILES_M * 4, 256, 0, stream>>>(A, Bt, xb, out, cnt, b_rel, b_self,
                                                     typeoff, rowmap);
}

// Round 17
// 163.678 us; speedup vs baseline: 1.0883x; 1.0525x over previous
//
#include <hip/hip_runtime.h>
#include <hip/hip_bf16.h>

#define N_NODES 20000
#define N_EDGES 150000
#define D 512
#define KK 2048          // GEMM K: 3 rel slots (in A) + 1 self slot (from xb)
#define KREL 1536        // A row stride (3 rel slots only)
#define NROWS 20480
#define NTILES_M 320     // 64-row M tiles

typedef __attribute__((ext_vector_type(8))) short bf16x8_t;
typedef __attribute__((ext_vector_type(4))) float f32x4_t;

// ---- helpers ----
__device__ __forceinline__ unsigned short f2bf(float x) {
    unsigned u = __float_as_uint(x);
    unsigned r = u + 0x7fffu + ((u >> 16) & 1u);   // RNE
    return (unsigned short)(r >> 16);
}
__device__ __forceinline__ unsigned pack2(float a, float b) {
    return (unsigned)f2bf(a) | ((unsigned)f2bf(b) << 16);
}
__device__ __forceinline__ float bflo(unsigned u) { return __uint_as_float(u << 16); }
__device__ __forceinline__ float bfhi(unsigned u) { return __uint_as_float(u & 0xffff0000u); }

#define GL(g, l)                                                                        \
    __builtin_amdgcn_global_load_lds(                                                   \
        (const __attribute__((address_space(1))) unsigned*)(g),                         \
        (__attribute__((address_space(3))) unsigned*)(l), 16, 0, 0)

// ---- fused prep: transpose_B (384 blocks) | conv_x (5000) | count (587) ----
#define TB_BLOCKS 384
#define CX_BLOCKS 5000
#define CNT_BLOCKS 587
__global__ __launch_bounds__(256) void fused_prep(
    const float* __restrict__ W_rel, const float* __restrict__ W_self,
    short* __restrict__ Bt,
    const float* __restrict__ x, short* __restrict__ xb,
    const int* __restrict__ edst, int* __restrict__ hist,
    const int* __restrict__ ntype, int* __restrict__ tcnt) {
    __shared__ float tile[64][65];
    const int b = blockIdx.x;
    if (b < TB_BLOCKS) {
        const int z = b >> 6;                         // 0..5
        const int rem = b & 63;
        const int e0 = (rem & 7) * 64, d0 = (rem >> 3) * 64;
        const float* src = (z < 3) ? (W_rel + (size_t)z * D * D)
                                   : (W_self + (size_t)(z - 3) * D * D);
        const int cbase = (z < 3) ? z * 512 : KREL + (z - 3) * 512;
        const int tx = threadIdx.x & 63, ty = threadIdx.x >> 6;
#pragma unroll
        for (int j = 0; j < 16; ++j) {
            int dl = ty * 16 + j;
            tile[dl][tx] = src[(size_t)(d0 + dl) * D + e0 + tx];
        }
        __syncthreads();
#pragma unroll
        for (int j = 0; j < 16; ++j) {
            int el = ty * 16 + j;
            Bt[(size_t)(e0 + el) * 3072 + cbase + d0 + tx] = (short)f2bf(tile[tx][el]);
        }
    } else if (b < TB_BLOCKS + CX_BLOCKS) {
        int idx = (b - TB_BLOCKS) * 256 + threadIdx.x;   // < 1,280,000
        const float4* s = (const float4*)x + (size_t)idx * 2;
        float4 a = s[0], bb = s[1];
        uint4 pk;
        pk.x = pack2(a.x, a.y);  pk.y = pack2(a.z, a.w);
        pk.z = pack2(bb.x, bb.y); pk.w = pack2(bb.z, bb.w);
        ((uint4*)xb)[idx] = pk;
    } else {
        int i = (b - TB_BLOCKS - CX_BLOCKS) * 256 + threadIdx.x;
        if (i < N_EDGES) atomicAdd(&hist[edst[i]], 1);
        int lane = threadIdx.x & 63;
        int t = (i < N_NODES) ? ntype[i] : 3;
        unsigned long long m0 = __ballot(t == 0), m1 = __ballot(t == 1), m2 = __ballot(t == 2);
        if (lane == 0) {
            if (m0) atomicAdd(&tcnt[0], __popcll(m0));
            if (m1) atomicAdd(&tcnt[1], __popcll(m1));
            if (m2) atomicAdd(&tcnt[2], __popcll(m2));
        }
    }
}

// ---- scan of 20000 edge-bins -> offs/cur; typeoff; rowmap padding marks ----
__global__ __launch_bounds__(1024) void scan_k(const int* __restrict__ hist,
                                               int* __restrict__ offs,
                                               int* __restrict__ cur,
                                               const int* __restrict__ tcnt,
                                               int* __restrict__ typeoff,
                                               int* __restrict__ rowmap) {
    __shared__ int part[1024];
    const int t = threadIdx.x;
    const int base = t * 20;
    int local[20];
    int sum = 0;
#pragma unroll
    for (int i = 0; i < 20; ++i) {
        int b = base + i;
        int v = (b < N_NODES) ? hist[b] : 0;
        local[i] = sum;
        sum += v;
    }
    part[t] = sum;
    __syncthreads();
    for (int off = 1; off < 1024; off <<= 1) {
        int v = part[t];
        int u = (t >= off) ? part[t - off] : 0;
        __syncthreads();
        part[t] = v + u;
        __syncthreads();
    }
    int tbase = (t > 0) ? part[t - 1] : 0;
#pragma unroll
    for (int i = 0; i < 20; ++i) {
        int b = base + i;
        if (b < N_NODES) {
            int o = tbase + local[i];
            offs[b] = o;
            cur[b] = o;
        }
    }
    if (t == 1023) offs[N_NODES] = part[1023];

    int c0 = tcnt[0], c1 = tcnt[1], c2 = tcnt[2];
    int o1 = (c0 + 127) & ~127;
    int o2 = o1 + ((c1 + 127) & ~127);
    int o3 = o2 + ((c2 + 127) & ~127);
    if (t == 0) { typeoff[0] = 0; typeoff[1] = o1; typeoff[2] = o2; typeoff[3] = o3; }
    int p0 = o1 - c0, p1 = o2 - o1 - c1, p2 = o3 - o2 - c2;
    if (t < p0) rowmap[c0 + t] = -1;
    else if (t < p0 + p1) rowmap[o1 + c1 + (t - p0)] = -1;
    else if (t - p0 - p1 < p2) rowmap[o2 + c2 + (t - p0 - p1)] = -1;
}

// ---- node->row assignment (type-grouped) + edge-id scatter (fused) ----
__global__ __launch_bounds__(256) void assign_scatter_k(
    const int* __restrict__ ntype, const int* __restrict__ typeoff,
    int* __restrict__ tcur, int* __restrict__ noderow, int* __restrict__ rowmap,
    const int* __restrict__ esrc, const int* __restrict__ edst,
    const int* __restrict__ etyp, int* __restrict__ cur, int* __restrict__ sorted) {
    int i = blockIdx.x * 256 + threadIdx.x;
    int lane = threadIdx.x & 63;
    bool valid = i < N_NODES;
    int t = valid ? ntype[i] : 3;
    unsigned long long m0 = __ballot(t == 0), m1 = __ballot(t == 1), m2 = __ballot(t == 2);
    unsigned long long below = (lane == 0) ? 0ull : (~0ull >> (64 - lane));
    int b0 = 0, b1 = 0, b2 = 0;
    if (lane == 0) {
        if (m0) b0 = atomicAdd(&tcur[0], __popcll(m0));
        if (m1) b1 = atomicAdd(&tcur[1], __popcll(m1));
        if (m2) b2 = atomicAdd(&tcur[2], __popcll(m2));
    }
    b0 = __shfl(b0, 0); b1 = __shfl(b1, 0); b2 = __shfl(b2, 0);
    if (valid) {
        unsigned long long mk = (t == 0) ? m0 : (t == 1) ? m1 : m2;
        int bs = (t == 0) ? b0 : (t == 1) ? b1 : b2;
        int row = typeoff[t] + bs + __popcll(mk & below);
        noderow[i] = row;
        rowmap[row] = i;
    }
    if (i < N_EDGES) {
        int dst = edst[i];
        int pos = atomicAdd(&cur[dst], 1);
        sorted[pos] = esrc[i] | (etyp[i] << 16);
    }
}

// ---- aggregate: 2 nodes per wave, 8 gathers in flight; linear A writes ----
#define DECL_ACC(P)                                                                   \
    float P##00=0,P##01=0,P##02=0,P##03=0,P##04=0,P##05=0,P##06=0,P##07=0,            \
          P##10=0,P##11=0,P##12=0,P##13=0,P##14=0,P##15=0,P##16=0,P##17=0,            \
          P##20=0,P##21=0,P##22=0,P##23=0,P##24=0,P##25=0,P##26=0,P##27=0;            \
    int P##c0=0, P##c1=0, P##c2=0;

#define ACC_E(P, r, v) {                                                              \
    float f0=bflo(v.x),f1=bfhi(v.x),f2=bflo(v.y),f3=bfhi(v.y);                        \
    float f4=bflo(v.z),f5=bfhi(v.z),f6=bflo(v.w),f7=bfhi(v.w);                        \
    if ((r)==0){P##00+=f0;P##01+=f1;P##02+=f2;P##03+=f3;P##04+=f4;P##05+=f5;P##06+=f6;P##07+=f7;P##c0++;} \
    else if ((r)==1){P##10+=f0;P##11+=f1;P##12+=f2;P##13+=f3;P##14+=f4;P##15+=f5;P##16+=f6;P##17+=f7;P##c1++;} \
    else {P##20+=f0;P##21+=f1;P##22+=f2;P##23+=f3;P##24+=f4;P##25+=f5;P##26+=f6;P##27+=f7;P##c2++;} }

#define STORE_ACC(P, n) {                                                             \
    const int rowid = noderow[n];                                                     \
    short* row = A + (size_t)rowid * KREL;                                            \
    uint4 q;                                                                          \
    q.x=pack2(P##00,P##01); q.y=pack2(P##02,P##03); q.z=pack2(P##04,P##05); q.w=pack2(P##06,P##07); \
    *(uint4*)(row + 0 * D + lane * 8) = q;                                            \
    q.x=pack2(P##10,P##11); q.y=pack2(P##12,P##13); q.z=pack2(P##14,P##15); q.w=pack2(P##16,P##17); \
    *(uint4*)(row + 1 * D + lane * 8) = q;                                            \
    q.x=pack2(P##20,P##21); q.y=pack2(P##22,P##23); q.z=pack2(P##24,P##25); q.w=pack2(P##26,P##27); \
    *(uint4*)(row + 2 * D + lane * 8) = q;                                            \
    if (lane == 0) { cnt[n]=P##c0; cnt[N_NODES+n]=P##c1; cnt[2*N_NODES+n]=P##c2; } }

__global__ __launch_bounds__(256) void aggregate(const short* __restrict__ xb,
                                                 const int* __restrict__ offs,
                                                 const int* __restrict__ sorted,
                                                 const int* __restrict__ noderow,
                                                 short* __restrict__ A,
                                                 int* __restrict__ cnt) {
    const int wid = threadIdx.x >> 6, lane = threadIdx.x & 63;
    const int n0 = (blockIdx.x * 4 + wid) * 2;
    if (n0 >= N_NODES) return;
    const int n1 = n0 + 1;
    const int s0 = offs[n0], e0 = offs[n0 + 1];
    const int s1 = offs[n1], e1 = offs[n1 + 1];
    const int m0 = e0 - s0, m1 = e1 - s1;

    DECL_ACC(a); DECL_ACC(b);

    int pl0 = (lane < m0) ? sorted[s0 + lane] : 0;
    int pl1 = (lane < m1) ? sorted[s1 + lane] : 0;
    const int mm0 = m0 < 64 ? m0 : 64;
    const int mm1 = m1 < 64 ? m1 : 64;
    const int mmax = mm0 > mm1 ? mm0 : mm1;

    for (int i = 0; i < mmax; i += 4) {
        int pA0 = __shfl(pl0, i), pA1 = __shfl(pl0, i + 1);
        int pA2 = __shfl(pl0, i + 2), pA3 = __shfl(pl0, i + 3);
        int pB0 = __shfl(pl1, i), pB1 = __shfl(pl1, i + 1);
        int pB2 = __shfl(pl1, i + 2), pB3 = __shfl(pl1, i + 3);
        int iA0 = (i     < mm0) ? (pA0 & 0xffff) : 0;
        int iA1 = (i + 1 < mm0) ? (pA1 & 0xffff) : 0;
        int iA2 = (i + 2 < mm0) ? (pA2 & 0xffff) : 0;
        int iA3 = (i + 3 < mm0) ? (pA3 & 0xffff) : 0;
        int iB0 = (i     < mm1) ? (pB0 & 0xffff) : 0;
        int iB1 = (i + 1 < mm1) ? (pB1 & 0xffff) : 0;
        int iB2 = (i + 2 < mm1) ? (pB2 & 0xffff) : 0;
        int iB3 = (i + 3 < mm1) ? (pB3 & 0xffff) : 0;
        uint4 vA0 = ((const uint4*)(xb + (size_t)iA0 * D))[lane];
        uint4 vB0 = ((const uint4*)(xb + (size_t)iB0 * D))[lane];
        uint4 vA1 = ((const uint4*)(xb + (size_t)iA1 * D))[lane];
        uint4 vB1 = ((const uint4*)(xb + (size_t)iB1 * D))[lane];
        uint4 vA2 = ((const uint4*)(xb + (size_t)iA2 * D))[lane];
        uint4 vB2 = ((const uint4*)(xb + (size_t)iB2 * D))[lane];
        uint4 vA3 = ((const uint4*)(xb + (size_t)iA3 * D))[lane];
        uint4 vB3 = ((const uint4*)(xb + (size_t)iB3 * D))[lane];
        if (i     < mm0) ACC_E(a, pA0 >> 16, vA0);
        if (i     < mm1) ACC_E(b, pB0 >> 16, vB0);
        if (i + 1 < mm0) ACC_E(a, pA1 >> 16, vA1);
        if (i + 1 < mm1) ACC_E(b, pB1 >> 16, vB1);
        if (i + 2 < mm0) ACC_E(a, pA2 >> 16, vA2);
        if (i + 2 < mm1) ACC_E(b, pB2 >> 16, vB2);
        if (i + 3 < mm0) ACC_E(a, pA3 >> 16, vA3);
        if (i + 3 < mm1) ACC_E(b, pB3 >> 16, vB3);
    }
    for (int j = 64; j < m0; ++j) {      // overflow (essentially never taken)
        int p = sorted[s0 + j];
        uint4 v = ((const uint4*)(xb + (size_t)(p & 0xffff) * D))[lane];
        ACC_E(a, p >> 16, v);
    }
    for (int j = 64; j < m1; ++j) {
        int p = sorted[s1 + j];
        uint4 v = ((const uint4*)(xb + (size_t)(p & 0xffff) * D))[lane];
        ACC_E(b, p >> 16, v);
    }

    STORE_ACC(a, n0);
    STORE_ACC(b, n1);
}

// ---- GEMM: 64x128 tile, BK=128, single 48KB buffer, 2-barrier loop (R13) ----
__global__ __launch_bounds__(256, 3) void gemm_bias_relu(
    const short* __restrict__ A, const short* __restrict__ Bt,
    const short* __restrict__ xb, float* __restrict__ out,
    const int* __restrict__ cnt, const float* __restrict__ b_rel,
    const float* __restrict__ b_self, const int* __restrict__ typeoff,
    const int* __restrict__ rowmap) {
    __shared__ short lds[24576];         // A: 64x128 (16KB) then B: 128x128 (32KB)
    const int tid = threadIdx.x;
    const int lane = tid & 63;
    const int wid = tid >> 6;
    const int wm = wid >> 1, wn = wid & 1;
    const int lr = lane & 15, lk = lane >> 4;

    // bijective XCD-chunk swizzle: 1280 blocks, 8 XCDs, 160/XCD; tn-siblings adjacent
    const int lin = blockIdx.x;
    const int mapped = (lin & 7) * 160 + (lin >> 3);
    const int tm = mapped >> 2;
    const int tn = mapped & 3;

    const int o1 = typeoff[1], o2 = typeoff[2], Mtot = typeoff[3];
    const int arow0 = tm * 64;
    if (arow0 >= Mtot) return;
    const int ttile = (arow0 >= o2) ? 2 : (arow0 >= o1) ? 1 : 0;
    const int tsel = ttile * 512;
    const int brow0 = tn * 128;

    // staging: A 4 chunks + B 8 chunks per thread; LDS[row][c] = data[row][c^(row&15)]
    const short* aP[4]; const short* xP[4]; const short* bP[8];
#pragma unroll
    for (int j = 0; j < 4; ++j) {
        int p = tid + 256 * j;                  // 0..1023
        int row = p >> 4;                       // 0..63
        int g = (p & 15) ^ (row & 15);
        aP[j] = A + (size_t)(arow0 + row) * KREL + g * 8;
        int nd = rowmap[arow0 + row];
        if (nd < 0) nd = 0;
        xP[j] = xb + (size_t)nd * D + g * 8;
    }
#pragma unroll
    for (int j = 0; j < 8; ++j) {
        int p = tid + 256 * j;                  // 0..2047
        int row = p >> 4;                       // 0..127
        int g = (p & 15) ^ (row & 15);
        bP[j] = Bt + (size_t)(brow0 + row) * 3072 + g * 8;
    }
    char* const ldsc = (char*)lds;

#define STAGE(kt) {                                                                   \
    const int k0s = (kt) * 128;                                                       \
    if (k0s < KREL) {                                                                 \
        _Pragma("unroll")                                                             \
        for (int j = 0; j < 4; ++j)                                                   \
            GL(aP[j] + k0s, ldsc + (tid + 256 * j) * 16);                             \
    } else {                                                                          \
        _Pragma("unroll")                                                             \
        for (int j = 0; j < 4; ++j)                                                   \
            GL(xP[j] + (k0s - KREL), ldsc + (tid + 256 * j) * 16);                    \
    }                                                                                 \
    const int bk = k0s + (k0s >= KREL ? tsel : 0);                                    \
    _Pragma("unroll")                                                                 \
    for (int j = 0; j < 8; ++j)                                                       \
        GL(bP[j] + bk, ldsc + 16384 + (tid + 256 * j) * 16);                          \
}

#define COMPUTE() {                                                                   \
    _Pragma("unroll")                                                                 \
    for (int kk = 0; kk < 4; ++kk) {                                                  \
        bf16x8_t af[2], bfr[4];                                                       \
        _Pragma("unroll")                                                             \
        for (int m = 0; m < 2; ++m) {                                                 \
            int row_l = wm * 32 + m * 16 + lr;                                        \
            int pos = (row_l << 4) + ((kk * 4 + lk) ^ (row_l & 15));                  \
            af[m] = *(const bf16x8_t*)&lds[pos << 3];                                 \
        }                                                                             \
        _Pragma("unroll")                                                             \
        for (int n = 0; n < 4; ++n) {                                                 \
            int row_l = wn * 64 + n * 16 + lr;                                        \
            int pos = (row_l << 4) + ((kk * 4 + lk) ^ (row_l & 15));                  \
            bfr[n] = *(const bf16x8_t*)&lds[8192 + (pos << 3)];                       \
        }                                                                             \
        __builtin_amdgcn_s_setprio(1);                                                \
        _Pragma("unroll")                                                             \
        for (int m = 0; m < 2; ++m)                                                   \
            _Pragma("unroll")                                                         \
            for (int n = 0; n < 4; ++n)                                               \
                acc[m][n] = __builtin_amdgcn_mfma_f32_16x16x32_bf16(                  \
                    af[m], bfr[n], acc[m][n], 0, 0, 0);                               \
        __builtin_amdgcn_s_setprio(0);                                                \
    }                                                                                 \
}

    f32x4_t acc[2][4] = {};

    STAGE(0);
    __syncthreads();             // vmcnt-drain + barrier: tile 0 ready
#pragma unroll 1
    for (int kt = 0; kt < 16; ++kt) {
        COMPUTE();
        __syncthreads();         // all waves done reading before overwrite
        if (kt + 1 < 16) {
            STAGE(kt + 1);
            __syncthreads();     // drain + barrier: next tile ready
        }
    }

#pragma unroll
    for (int m = 0; m < 2; ++m) {
#pragma unroll
        for (int q = 0; q < 4; ++q) {
            int rowg = arow0 + wm * 32 + m * 16 + lk * 4 + q;
            int node = rowmap[rowg];
            if (node < 0) continue;
            float c0 = (float)cnt[node];
            float c1 = (float)cnt[N_NODES + node];
            float c2 = (float)cnt[2 * N_NODES + node];
#pragma unroll
            for (int n = 0; n < 4; ++n) {
                int colg = tn * 128 + wn * 64 + n * 16 + lr;
                float v = acc[m][n][q];
                v += c0 * b_rel[colg] + c1 * b_rel[D + colg] + c2 * b_rel[2 * D + colg];
                v += b_self[tsel + colg];
                v = v > 0.f ? v : 0.f;
                out[(size_t)node * D + colg] = v;
            }
        }
    }
}

extern "C" void kernel_launch(void* const* d_in, const int* in_sizes, int n_in,
                              void* d_out, int out_size, void* d_ws, size_t ws_size,
                              hipStream_t stream) {
    const float* x      = (const float*)d_in[0];
    const float* W_rel  = (const float*)d_in[1];
    const float* b_rel  = (const float*)d_in[2];
    const float* W_self = (const float*)d_in[3];
    const float* b_self = (const float*)d_in[4];
    const int* esrc     = (const int*)d_in[5];
    const int* edst     = (const int*)d_in[6];
    const int* etyp     = (const int*)d_in[7];
    const int* ntyp     = (const int*)d_in[8];
    float* out = (float*)d_out;

    char* ws = (char*)d_ws;
    size_t o = 0;
    short* A       = (short*)(ws + o); o += (size_t)NROWS * KREL * 2;    // 62,914,560
    short* Bt      = (short*)(ws + o); o += (size_t)D * 3072 * 2;        // 3,145,728
    short* xb      = (short*)(ws + o); o += (size_t)N_NODES * D * 2;     // 20,480,000
    int*   cnt     = (int*)(ws + o);   o += (size_t)3 * N_NODES * 4;     // 240,000
    int*   offs    = (int*)(ws + o);   o += 80032;
    int*   cur     = (int*)(ws + o);   o += 80000;
    int*   noderow = (int*)(ws + o);   o += 80000;
    int*   rowmap  = (int*)(ws + o);   o += (size_t)NROWS * 4;           // 81,920
    int*   sorted  = (int*)(ws + o);   o += 600000;
    // zero-region (memset): hist + tcnt + tcur + typeoff, contiguous 80048 B
    int*   hist    = (int*)(ws + o);   o += 80000;
    int*   tcnt    = (int*)(ws + o);   o += 16;
    int*   tcur    = (int*)(ws + o);   o += 16;
    int*   typeoff = (int*)(ws + o);   o += 16;

    hipMemsetAsync(hist, 0, 80048, stream);
    fused_prep<<<TB_BLOCKS + CX_BLOCKS + CNT_BLOCKS, 256, 0, stream>>>(
        W_rel, W_self, Bt, x, xb, edst, hist, ntyp, tcnt);
    scan_k<<<1, 1024, 0, stream>>>(hist, offs, cur, tcnt, typeoff, rowmap);
    assign_scatter_k<<<(N_EDGES + 255) / 256, 256, 0, stream>>>(
        ntyp, typeoff, tcur, noderow, rowmap, esrc, edst, etyp, cur, sorted);
    aggregate<<<(N_NODES / 2 + 3) / 4, 256, 0, stream>>>(xb, offs, sorted, noderow, A, cnt);
    gemm_bias_relu<<<NTILES_M * 4, 256, 0, stream>>>(A, Bt, xb, out, cnt, b_rel, b_self,
                                                     typeoff, rowmap);
}